// Round 1
// baseline (226.219 us; speedup 1.0000x reference)
//
#include <hip/hip_runtime.h>
#include <math.h>

#define EDIM 128
#define NATOM 128
#define NBATCH 512
#define THREADS 512
#define SLDS 132          // padded LDS row stride in floats (16B-aligned rows)
#define ROWLEN 257        // kx innermost length = 2E+1

__device__ __forceinline__ float fast_ssp(float x) {
    // softplus(x) - log(2), numerically stable
    return fmaxf(x, 0.f) + __logf(1.f + __expf(-fabsf(x))) - 0.69314718055994531f;
}

__global__ void __launch_bounds__(THREADS, 1)
gen_actions_kernel(const float* __restrict__ kx,
                   const float* __restrict__ pos,
                   const float* __restrict__ mask,
                   const float* __restrict__ scale_ptr,
                   const float* __restrict__ evala,
                   const float* __restrict__ Wx,
                   const float* __restrict__ bx,
                   const float* __restrict__ Wk,
                   const float* __restrict__ bk,
                   float* __restrict__ out)
{
    extern __shared__ float dynbuf[];
    float* bufA = dynbuf;                  // [128][132] : act_x -> X^T
    float* bufB = dynbuf + NATOM * SLDS;   // [128][132] : act_k -> K^T
    __shared__ float posXs[NATOM], posYs[NATOM], posZs[NATOM], lsBs[NATOM];
    __shared__ float amBs[NATOM * 3];
    __shared__ float redBs[2];
    __shared__ int   cntBs[2];

    const int b = blockIdx.x;
    const int t = threadIdx.x;

    // ---------------- phase 1: count + positions + zero accumulators
    if (t < NATOM) {
        float m = mask[b * NATOM + t];
        unsigned long long bal = __ballot(m > 0.5f);
        if ((t & 63) == 0) cntBs[t >> 6] = __popcll(bal);
        const float* p = pos + ((size_t)b * NATOM + t) * 3;
        posXs[t] = p[0]; posYs[t] = p[1]; posZs[t] = p[2];
    }
    if (t < NATOM * 3) amBs[t] = 0.f;
    __syncthreads();
    const int count = cntBs[0] + cntBs[1];   // mask is a contiguous prefix

    // ---------------- phase 2: stream kx (aligned float4 over flat slice),
    // apply mask + activations, scatter into LDS row-major buffers
    {
        const float4* kx4 = (const float4*)(kx + (size_t)b * (NATOM * ROWLEN));
        auto proc = [&](int g, float val) {
            unsigned gu = (unsigned)g;
            unsigned i = gu / 257u;              // compiler magic-div
            unsigned r = gu - i * 257u;
            val = ((int)i < count) ? val : 0.f;  // kx * atoms_mask
            if (r < 128u) {
                bufA[i * SLDS + r] = fast_ssp(val);
            } else if (r < 256u) {
                bufB[i * SLDS + (r - 128u)] = fmaxf(val, 0.f);
            } else {
                lsBs[i] = val;
            }
        };
        for (int g4 = t; g4 < (NATOM * ROWLEN) / 4; g4 += THREADS) {
            float4 v = kx4[g4];
            int g = g4 * 4;
            proc(g + 0, v.x);
            proc(g + 1, v.y);
            proc(g + 2, v.z);
            proc(g + 3, v.w);
        }
    }
    __syncthreads();

    // ---------------- phase 3: X = act_x @ Wx^T + bx ; K = act_k @ Wk^T + bk
    // thread owns feature column o and a 32-atom strip; W rows from global (L2)
    {
        const int o = t & 127;
        const int strip = t >> 7;      // 0..3
        const int ibase = strip * 32;
        float accA[32], accB[32];
        #pragma unroll
        for (int q = 0; q < 32; ++q) { accA[q] = 0.f; accB[q] = 0.f; }
        const float* wxr = Wx + o * EDIM;
        const float* wkr = Wk + o * EDIM;
        float4 wx4 = *(const float4*)(wxr);
        float4 wk4 = *(const float4*)(wkr);
        for (int e0 = 0; e0 < EDIM; e0 += 4) {
            // prefetch next W chunk (wraps harmlessly on last iter)
            float4 wxn = *(const float4*)(wxr + ((e0 + 4) & 127));
            float4 wkn = *(const float4*)(wkr + ((e0 + 4) & 127));
            const float* pA = bufA + ibase * SLDS + e0;
            const float* pB = bufB + ibase * SLDS + e0;
            #pragma unroll
            for (int q = 0; q < 32; ++q) {
                float4 a4 = *(const float4*)(pA + q * SLDS);
                accA[q] += wx4.x*a4.x + wx4.y*a4.y + wx4.z*a4.z + wx4.w*a4.w;
            }
            #pragma unroll
            for (int q = 0; q < 32; ++q) {
                float4 b4 = *(const float4*)(pB + q * SLDS);
                accB[q] += wk4.x*b4.x + wk4.y*b4.y + wk4.z*b4.z + wk4.w*b4.w;
            }
            wx4 = wxn; wk4 = wkn;
        }
        float bxo = bx[o], bko = bk[o];
        __syncthreads();   // all reads of activations done before overwrite
        #pragma unroll
        for (int q4 = 0; q4 < 8; ++q4) {
            float4 wv, kv;
            wv.x = accA[q4*4+0] + bxo; wv.y = accA[q4*4+1] + bxo;
            wv.z = accA[q4*4+2] + bxo; wv.w = accA[q4*4+3] + bxo;
            kv.x = accB[q4*4+0] + bko; kv.y = accB[q4*4+1] + bko;
            kv.z = accB[q4*4+2] + bko; kv.w = accB[q4*4+3] + bko;
            *(float4*)(bufA + o * SLDS + ibase + q4*4) = wv;  // transposed: [feat][atom]
            *(float4*)(bufB + o * SLDS + ibase + q4*4) = kv;
        }
        __syncthreads();
    }

    // ---------------- phase 4: Gram matrices + pairwise forces -> actions_mean
    {
        const int jg = t & 31;           // j-quad id
        const int j0 = jg * 4;
        const int istrip = t >> 5;       // 0..15, each owns 8 atoms (2 i-blocks of 4)
        const float inv_sqrt_e = 0.08838834764831845f;   // 1/sqrt(128)
        float amL[12];
        #pragma unroll
        for (int q = 0; q < 12; ++q) amL[q] = 0.f;
        float pjx[4], pjy[4], pjz[4];
        #pragma unroll
        for (int jj = 0; jj < 4; ++jj) {
            pjx[jj] = posXs[j0 + jj];
            pjy[jj] = posYs[j0 + jj];
            pjz[jj] = posZs[j0 + jj];
        }
        if (j0 < count) {
            for (int ib = 0; ib < 2; ++ib) {
                const int i0 = istrip * 8 + ib * 4;
                if (i0 >= count) break;
                float sx[16], sk[16];
                #pragma unroll
                for (int q = 0; q < 16; ++q) { sx[q] = 0.f; sk[q] = 0.f; }
                const float* pAj = bufA + j0;
                const float* pAi = bufA + i0;
                const float* pBj = bufB + j0;
                const float* pBi = bufB + i0;
                #pragma unroll 2
                for (int e = 0; e < EDIM; ++e) {
                    float4 xj = *(const float4*)(pAj + e * SLDS);
                    float4 xi = *(const float4*)(pAi + e * SLDS);
                    float4 kj = *(const float4*)(pBj + e * SLDS);
                    float4 ki = *(const float4*)(pBi + e * SLDS);
                    float xis[4] = {xi.x, xi.y, xi.z, xi.w};
                    float xjs[4] = {xj.x, xj.y, xj.z, xj.w};
                    float kis[4] = {ki.x, ki.y, ki.z, ki.w};
                    float kjs[4] = {kj.x, kj.y, kj.z, kj.w};
                    #pragma unroll
                    for (int ii = 0; ii < 4; ++ii) {
                        #pragma unroll
                        for (int jj = 0; jj < 4; ++jj) {
                            sx[ii*4+jj] = fmaf(xis[ii], xjs[jj], sx[ii*4+jj]);
                            sk[ii*4+jj] = fmaf(kis[ii], kjs[jj], sk[ii*4+jj]);
                        }
                    }
                }
                #pragma unroll
                for (int ii = 0; ii < 4; ++ii) {
                    const int i = i0 + ii;
                    float pix = posXs[i], piy = posYs[i], piz = posZs[i];
                    #pragma unroll
                    for (int jj = 0; jj < 4; ++jj) {
                        const int j = j0 + jj;
                        float dx = pjx[jj] - pix;
                        float dy = pjy[jj] - piy;
                        float dz = pjz[jj] - piz;
                        float r2 = fmaf(dx, dx, fmaf(dy, dy, dz*dz)) + 1e-16f;
                        float rr = sqrtf(r2);
                        bool ok = (i < count) && (j < count) && (rr < 5.0f);
                        float fc = ok ? (0.5f * (__cosf(rr * 0.62831853071795865f) + 1.f)) : 0.f;
                        float xs = (rr - sx[ii*4+jj] * inv_sqrt_e) * 0.5f;
                        float fv = xs * (sk[ii*4+jj] * inv_sqrt_e) * fc;
                        float w = fv / (rr + 1e-8f);   // P = d * 1/(r+1e-8)
                        amL[jj*3+0] = fmaf(dx, w, amL[jj*3+0]);
                        amL[jj*3+1] = fmaf(dy, w, amL[jj*3+1]);
                        amL[jj*3+2] = fmaf(dz, w, amL[jj*3+2]);
                    }
                }
            }
            #pragma unroll
            for (int jj = 0; jj < 4; ++jj) {
                if (j0 + jj < count) {
                    atomicAdd(&amBs[(j0+jj)*3+0], amL[jj*3+0]);
                    atomicAdd(&amBs[(j0+jj)*3+1], amL[jj*3+1]);
                    atomicAdd(&amBs[(j0+jj)*3+2], amL[jj*3+2]);
                }
            }
        }
    }
    __syncthreads();

    // ---------------- phase 5: epilogue (tanh-normalize, log-prob, outputs)
    float lp = 0.f;
    if (t < NATOM) {
        const int j = t;
        float m = mask[b * NATOM + j];
        const float* ev = evala + ((size_t)b * NATOM + j) * 3;
        float e0v = ev[0], e1v = ev[1], e2v = ev[2];
        float* op = out + ((size_t)b * NATOM + j) * 3;
        op[0] = e0v * m; op[1] = e1v * m; op[2] = e2v * m;
        if (j < count) {
            float scale = scale_ptr[0];
            float ax = amBs[j*3+0], ay = amBs[j*3+1], az = amBs[j*3+2];
            float nrm = sqrtf(fmaf(ax, ax, fmaf(ay, ay, az*az)) + 1e-16f) + 1e-8f;
            float q = __expf(-2.f * nrm);                // tanh(nrm), nrm>0
            float th = (1.f - q) / (1.f + q);
            float sc = th / nrm * scale;
            float mux = ax * sc, muy = ay * sc, muz = az * sc;
            float ls = fminf(fmaxf(lsBs[j], -20.f), 2.f);
            float sig = __expf(ls) * scale;
            float sinv = 1.f / sig;
            float lsg = __logf(sig);
            float zx = (e0v - mux) * sinv;
            float zy = (e1v - muy) * sinv;
            float zz = (e2v - muz) * sinv;
            lp = -0.5f * (zx*zx + zy*zy + zz*zz) - 3.f * lsg
                 - 3.f * 0.91893853320467274f;           // 0.5*log(2*pi)
        }
    }
    #pragma unroll
    for (int off = 32; off > 0; off >>= 1) lp += __shfl_down(lp, off);
    if (t == 0)  redBs[0] = lp;
    if (t == 64) redBs[1] = lp;
    __syncthreads();
    if (t == 0) out[(size_t)NBATCH * NATOM * 3 + b] = redBs[0] + redBs[1];
}

extern "C" void kernel_launch(void* const* d_in, const int* in_sizes, int n_in,
                              void* d_out, int out_size, void* d_ws, size_t ws_size,
                              hipStream_t stream) {
    const float* kx    = (const float*)d_in[0];
    const float* pos   = (const float*)d_in[1];
    const float* mask  = (const float*)d_in[2];
    const float* scale = (const float*)d_in[3];
    const float* ev    = (const float*)d_in[4];
    const float* Wx    = (const float*)d_in[5];
    const float* bx    = (const float*)d_in[6];
    const float* Wk    = (const float*)d_in[7];
    const float* bk    = (const float*)d_in[8];
    float* out = (float*)d_out;

    const size_t shbytes = (size_t)2 * NATOM * SLDS * sizeof(float);  // 135168 B dynamic
    // Allow >64KB dynamic LDS (gfx950 has 160KB/workgroup). Capture-safe: not a stream op.
    (void)hipFuncSetAttribute((const void*)gen_actions_kernel,
                              hipFuncAttributeMaxDynamicSharedMemorySize,
                              (int)shbytes);
    hipLaunchKernelGGL(gen_actions_kernel, dim3(NBATCH), dim3(THREADS), shbytes, stream,
                       kx, pos, mask, scale, ev, Wx, bx, Wk, bk, out);
}

// Round 2
// 92.522 us; speedup vs baseline: 2.4450x; 2.4450x over previous
//
#include <hip/hip_runtime.h>
#include <math.h>

#define EDIM 128
#define NATOM 128
#define NBATCH 512
#define THREADS 512
#define ROWLEN 257

typedef __attribute__((ext_vector_type(8))) short bf16x8;           // 8 bf16 (4 VGPRs)
typedef __attribute__((ext_vector_type(4))) float f32x4;            // MFMA C/D frag
typedef __attribute__((ext_vector_type(4))) unsigned short u16x4;   // 8B packed bf16
typedef float f4u __attribute__((ext_vector_type(4), aligned(4)));  // 4B-aligned float4 load

__device__ __forceinline__ unsigned short f2bf(float f) {       // RNE float->bf16
    unsigned u = __float_as_uint(f);
    u += 0x7FFFu + ((u >> 16) & 1u);
    return (unsigned short)(u >> 16);
}
__device__ __forceinline__ float bf2f(unsigned short h) {
    return __uint_as_float(((unsigned)h) << 16);
}
__device__ __forceinline__ float fast_ssp(float x) {            // softplus(x)-log2, stable
    return fmaxf(x, 0.f) + __logf(1.f + __expf(-fabsf(x))) - 0.69314718055994531f;
}
// XOR swizzle: row-major [128][256B] bf16 plane, byte ^= (row&7)<<4 -> b128 row-strided
// reads/writes spread over 8 16B slots (2-way max = free). Same map on write & read.
__device__ __forceinline__ int swz(int row, int cbyte) {
    return row * 256 + (cbyte ^ ((row & 7) << 4));
}

// LDS plane byte offsets (4 x 32KB = 128KB dynamic)
#define PH 0        // act_x hi  -> X hi
#define PL 32768    // act_x lo  -> X lo
#define QH 65536    // act_k hi  -> K hi
#define QL 98304    // act_k lo  -> K lo

__global__ void wsplit_kernel(const float* __restrict__ Wx,
                              const float* __restrict__ Wk,
                              unsigned short* __restrict__ ws) {
    int g = blockIdx.x * 256 + threadIdx.x;          // 0..32767
    const float* src = (g < 16384) ? Wx : Wk;
    int idx = g & 16383;
    float v = src[idx];
    unsigned short h = f2bf(v);
    unsigned short l = f2bf(v - bf2f(h));
    int base = (g < 16384) ? 0 : 32768;
    ws[base + idx] = h;
    ws[base + 16384 + idx] = l;
}

__global__ void __launch_bounds__(THREADS, 1)
gen_actions_kernel(const float* __restrict__ kx,
                   const float* __restrict__ pos,
                   const float* __restrict__ mask,
                   const float* __restrict__ scale_ptr,
                   const float* __restrict__ evala,
                   const float* __restrict__ bx,
                   const float* __restrict__ bk,
                   const unsigned short* __restrict__ ws,
                   float* __restrict__ out)
{
    extern __shared__ char lds[];
    __shared__ float posXs[NATOM], posYs[NATOM], posZs[NATOM], lsBs[NATOM];
    __shared__ float amBs[NATOM * 3];
    __shared__ float redBs[2];
    __shared__ int   cntBs[2];

    const int b = blockIdx.x;
    const int t = threadIdx.x;
    const int lane = t & 63;
    const int w = t >> 6;            // wave 0..7
    const int wr = w >> 2;           // wave row: M-dim (features / atoms-i), 0..1
    const int wc = w & 3;            // wave col: N-dim (atoms-j), 0..3
    const int l15 = lane & 15;
    const int l4  = lane >> 4;

    // ---------------- P1: count, positions, zero accumulators
    if (t < NATOM) {
        float m = mask[b * NATOM + t];
        unsigned long long bal = __ballot(m > 0.5f);
        if ((t & 63) == 0) cntBs[t >> 6] = __popcll(bal);
        const float* p = pos + ((size_t)b * NATOM + t) * 3;
        posXs[t] = p[0]; posYs[t] = p[1]; posZs[t] = p[2];
    }
    if (t < NATOM * 3) amBs[t] = 0.f;
    __syncthreads();
    const int count = cntBs[0] + cntBs[1];   // mask is a contiguous prefix

    // ---------------- P2: activations -> hi/lo bf16 planes in LDS
    // 4 threads per atom row; q<2 -> softplus (x part), q>=2 -> relu (k part).
    {
        const int i = t >> 2, q = t & 3;
        const float* row = kx + (size_t)b * (NATOM * ROWLEN) + i * ROWLEN + q * 64;
        const bool masked = (i >= count);
        char* baseH = lds + ((q < 2) ? PH : QH);
        char* baseL = lds + ((q < 2) ? PL : QL);
        const int cbase = (q & 1) * 64 + ((q < 2) ? 0 : -0) * 0;   // e-offset within plane
        const int ebase = (q < 2) ? q * 64 : (q - 2) * 64;
        (void)cbase;
        for (int j4 = 0; j4 < 16; ++j4) {
            f4u v = *(const f4u*)(row + j4 * 4);
            u16x4 hs, ls;
            #pragma unroll
            for (int c = 0; c < 4; ++c) {
                float x = masked ? 0.f : v[c];
                float a = (q < 2) ? fast_ssp(x) : fmaxf(x, 0.f);
                unsigned short h = f2bf(a);
                hs[c] = h;
                ls[c] = f2bf(a - bf2f(h));
            }
            int cb = (ebase + j4 * 4) * 2;
            *(u16x4*)(baseH + swz(i, cb)) = hs;
            *(u16x4*)(baseL + swz(i, cb)) = ls;
        }
        if (q == 3) {
            float v = row[64];                 // element 256 = log_std
            lsBs[i] = masked ? 0.f : v;
        }
    }
    __syncthreads();

    // ---------------- P3: X = act @ W^T + b, computed as D[o][atom] (swapped operands)
    // split-bf16: X = Wh*Ah + Wl*Ah + Wh*Al  (drop Wl*Al, rel err ~2^-16)
    for (int mat = 0; mat < 2; ++mat) {
        char* actH = lds + (mat ? QH : PH);
        char* actL = lds + (mat ? QL : PL);
        const unsigned short* WH = ws + mat * 32768;
        const unsigned short* WL = WH + 16384;
        const float* bias = mat ? bk : bx;
        const int n0 = wc * 32;                    // atom tile base (N-dim)
        f32x4 acc[4][2] = {};
        if (n0 < count) {
            for (int ks = 0; ks < 4; ++ks) {
                const int e0 = ks * 32 + l4 * 8;   // k-offset for this lane
                bf16x8 wh[4], wl[4], ah[2], al[2];
                #pragma unroll
                for (int mf = 0; mf < 4; ++mf) {
                    int orow = wr * 64 + mf * 16 + l15;
                    wh[mf] = *(const bf16x8*)(WH + orow * 128 + e0);
                    wl[mf] = *(const bf16x8*)(WL + orow * 128 + e0);
                }
                #pragma unroll
                for (int nf = 0; nf < 2; ++nf) {
                    int jrow = n0 + nf * 16 + l15;
                    ah[nf] = *(const bf16x8*)(actH + swz(jrow, e0 * 2));
                    al[nf] = *(const bf16x8*)(actL + swz(jrow, e0 * 2));
                }
                #pragma unroll
                for (int mf = 0; mf < 4; ++mf)
                    #pragma unroll
                    for (int nf = 0; nf < 2; ++nf) {
                        acc[mf][nf] = __builtin_amdgcn_mfma_f32_16x16x32_bf16(wh[mf], ah[nf], acc[mf][nf], 0, 0, 0);
                        acc[mf][nf] = __builtin_amdgcn_mfma_f32_16x16x32_bf16(wl[mf], ah[nf], acc[mf][nf], 0, 0, 0);
                        acc[mf][nf] = __builtin_amdgcn_mfma_f32_16x16x32_bf16(wh[mf], al[nf], acc[mf][nf], 0, 0, 0);
                    }
            }
        }
        __syncthreads();      // all act reads complete before overwrite
        if (n0 < count) {
            #pragma unroll
            for (int mf = 0; mf < 4; ++mf) {
                int ob = wr * 64 + mf * 16 + l4 * 4;         // 4 consecutive features
                f32x4 b4 = *(const f32x4*)(bias + ob);
                #pragma unroll
                for (int nf = 0; nf < 2; ++nf) {
                    int jrow = n0 + nf * 16 + l15;           // atom (D col)
                    u16x4 hs, ls;
                    #pragma unroll
                    for (int r = 0; r < 4; ++r) {
                        float v = acc[mf][nf][r] + b4[r];
                        unsigned short h = f2bf(v);
                        hs[r] = h;
                        ls[r] = f2bf(v - bf2f(h));
                    }
                    *(u16x4*)(actH + swz(jrow, ob * 2)) = hs;   // X[atom][o] hi
                    *(u16x4*)(actL + swz(jrow, ob * 2)) = ls;   // X[atom][o] lo
                }
            }
        }
        __syncthreads();
    }

    // ---------------- P4: Grams G = X@X^T, K@K^T (split-bf16) + pairwise epilogue
    const int m0g = wr * 64;       // i tile base
    const int n0g = wc * 32;       // j tile base
    f32x4 gx[4][2] = {}, gk[4][2] = {};
    const bool active = (m0g < count) && (n0g < count);
    if (active) {
        // X gram
        for (int ks = 0; ks < 4; ++ks) {
            const int e0b = (ks * 32 + l4 * 8) * 2;
            bf16x8 aH[4], aL[4], bH[2], bL[2];
            #pragma unroll
            for (int mf = 0; mf < 4; ++mf) {
                int irow = m0g + mf * 16 + l15;
                aH[mf] = *(const bf16x8*)(lds + PH + swz(irow, e0b));
                aL[mf] = *(const bf16x8*)(lds + PL + swz(irow, e0b));
            }
            #pragma unroll
            for (int nf = 0; nf < 2; ++nf) {
                int jrow = n0g + nf * 16 + l15;
                bH[nf] = *(const bf16x8*)(lds + PH + swz(jrow, e0b));
                bL[nf] = *(const bf16x8*)(lds + PL + swz(jrow, e0b));
            }
            #pragma unroll
            for (int mf = 0; mf < 4; ++mf)
                #pragma unroll
                for (int nf = 0; nf < 2; ++nf) {
                    gx[mf][nf] = __builtin_amdgcn_mfma_f32_16x16x32_bf16(aH[mf], bH[nf], gx[mf][nf], 0, 0, 0);
                    gx[mf][nf] = __builtin_amdgcn_mfma_f32_16x16x32_bf16(aH[mf], bL[nf], gx[mf][nf], 0, 0, 0);
                    gx[mf][nf] = __builtin_amdgcn_mfma_f32_16x16x32_bf16(aL[mf], bH[nf], gx[mf][nf], 0, 0, 0);
                }
        }
        // K gram
        for (int ks = 0; ks < 4; ++ks) {
            const int e0b = (ks * 32 + l4 * 8) * 2;
            bf16x8 aH[4], aL[4], bH[2], bL[2];
            #pragma unroll
            for (int mf = 0; mf < 4; ++mf) {
                int irow = m0g + mf * 16 + l15;
                aH[mf] = *(const bf16x8*)(lds + QH + swz(irow, e0b));
                aL[mf] = *(const bf16x8*)(lds + QL + swz(irow, e0b));
            }
            #pragma unroll
            for (int nf = 0; nf < 2; ++nf) {
                int jrow = n0g + nf * 16 + l15;
                bH[nf] = *(const bf16x8*)(lds + QH + swz(jrow, e0b));
                bL[nf] = *(const bf16x8*)(lds + QL + swz(jrow, e0b));
            }
            #pragma unroll
            for (int mf = 0; mf < 4; ++mf)
                #pragma unroll
                for (int nf = 0; nf < 2; ++nf) {
                    gk[mf][nf] = __builtin_amdgcn_mfma_f32_16x16x32_bf16(aH[mf], bH[nf], gk[mf][nf], 0, 0, 0);
                    gk[mf][nf] = __builtin_amdgcn_mfma_f32_16x16x32_bf16(aH[mf], bL[nf], gk[mf][nf], 0, 0, 0);
                    gk[mf][nf] = __builtin_amdgcn_mfma_f32_16x16x32_bf16(aL[mf], bH[nf], gk[mf][nf], 0, 0, 0);
                }
        }
        // pairwise epilogue directly on D-frags: lane column j fixed per nf
        const float inv_e = 0.08838834764831845f;            // 1/sqrt(128)
        #pragma unroll
        for (int nf = 0; nf < 2; ++nf) {
            const int j = n0g + nf * 16 + l15;
            const bool jvalid = (j < count);
            const float pjx = posXs[j], pjy = posYs[j], pjz = posZs[j];
            float amx = 0.f, amy = 0.f, amz = 0.f;
            #pragma unroll
            for (int mf = 0; mf < 4; ++mf) {
                #pragma unroll
                for (int r = 0; r < 4; ++r) {
                    const int i = m0g + mf * 16 + l4 * 4 + r;
                    float dx = pjx - posXs[i];
                    float dy = pjy - posYs[i];
                    float dz = pjz - posZs[i];
                    float r2 = fmaf(dx, dx, fmaf(dy, dy, dz * dz)) + 1e-16f;
                    float rr = sqrtf(r2);
                    bool ok = jvalid && (i < count) && (rr < 5.0f);
                    float fc = ok ? (0.5f * (__cosf(rr * 0.62831853071795865f) + 1.f)) : 0.f;
                    float xs = fmaf(gx[mf][nf][r], -0.044194173824159216f, rr * 0.5f);
                    float fv = xs * (gk[mf][nf][r] * inv_e) * fc;
                    float wgt = fv / (rr + 1e-8f);
                    amx = fmaf(dx, wgt, amx);
                    amy = fmaf(dy, wgt, amy);
                    amz = fmaf(dz, wgt, amz);
                }
            }
            amx += __shfl_xor(amx, 16); amx += __shfl_xor(amx, 32);
            amy += __shfl_xor(amy, 16); amy += __shfl_xor(amy, 32);
            amz += __shfl_xor(amz, 16); amz += __shfl_xor(amz, 32);
            if (l4 == 0 && jvalid) {
                atomicAdd(&amBs[j * 3 + 0], amx);
                atomicAdd(&amBs[j * 3 + 1], amy);
                atomicAdd(&amBs[j * 3 + 2], amz);
            }
        }
    }
    __syncthreads();

    // ---------------- P5: outputs
    // actions = eval * mask, vectorized float4 over [128][3]
    if (t < 96) {
        f32x4 ev4 = *(const f32x4*)(evala + (size_t)b * 384 + t * 4);
        f32x4 o4;
        #pragma unroll
        for (int c = 0; c < 4; ++c) {
            int atom = (t * 4 + c) / 3;
            o4[c] = (atom < count) ? ev4[c] : 0.f;
        }
        *(f32x4*)(out + (size_t)b * 384 + t * 4) = o4;
    }
    float lp = 0.f;
    if (t < NATOM && t < count) {
        const int j = t;
        const float* ev = evala + ((size_t)b * NATOM + j) * 3;
        float e0v = ev[0], e1v = ev[1], e2v = ev[2];
        float scale = scale_ptr[0];
        float ax = amBs[j * 3 + 0], ay = amBs[j * 3 + 1], az = amBs[j * 3 + 2];
        float nrm = sqrtf(fmaf(ax, ax, fmaf(ay, ay, az * az)) + 1e-16f) + 1e-8f;
        float qe = __expf(-2.f * nrm);
        float th = (1.f - qe) / (1.f + qe);
        float sc = th / nrm * scale;
        float mux = ax * sc, muy = ay * sc, muz = az * sc;
        float ls = fminf(fmaxf(lsBs[j], -20.f), 2.f);
        float sig = __expf(ls) * scale;
        float sinv = 1.f / sig;
        float lsg = __logf(sig);
        float zx = (e0v - mux) * sinv;
        float zy = (e1v - muy) * sinv;
        float zz = (e2v - muz) * sinv;
        lp = -0.5f * (zx * zx + zy * zy + zz * zz) - 3.f * lsg
             - 3.f * 0.91893853320467274f;
    }
    #pragma unroll
    for (int off = 32; off > 0; off >>= 1) lp += __shfl_down(lp, off);
    if (t == 0)  redBs[0] = lp;
    if (t == 64) redBs[1] = lp;
    __syncthreads();
    if (t == 0) out[(size_t)NBATCH * NATOM * 3 + b] = redBs[0] + redBs[1];
}

extern "C" void kernel_launch(void* const* d_in, const int* in_sizes, int n_in,
                              void* d_out, int out_size, void* d_ws, size_t ws_size,
                              hipStream_t stream) {
    const float* kx    = (const float*)d_in[0];
    const float* pos   = (const float*)d_in[1];
    const float* mask  = (const float*)d_in[2];
    const float* scale = (const float*)d_in[3];
    const float* ev    = (const float*)d_in[4];
    const float* Wx    = (const float*)d_in[5];
    const float* bx    = (const float*)d_in[6];
    const float* Wk    = (const float*)d_in[7];
    const float* bk    = (const float*)d_in[8];
    float* out = (float*)d_out;
    unsigned short* ws = (unsigned short*)d_ws;

    // W hi/lo split (128KB in d_ws), recomputed each launch (deterministic)
    hipLaunchKernelGGL(wsplit_kernel, dim3(128), dim3(256), 0, stream, Wx, Wk, ws);

    const size_t shbytes = 131072;   // 4 planes x 32KB dynamic LDS
    (void)hipFuncSetAttribute((const void*)gen_actions_kernel,
                              hipFuncAttributeMaxDynamicSharedMemorySize,
                              (int)shbytes);
    hipLaunchKernelGGL(gen_actions_kernel, dim3(NBATCH), dim3(THREADS), shbytes, stream,
                       kx, pos, mask, scale, ev, bx, bk, ws, out);
}

// Round 3
// 82.025 us; speedup vs baseline: 2.7579x; 1.1280x over previous
//
#include <hip/hip_runtime.h>
#include <math.h>

#define EDIM 128
#define NATOM 128
#define NBATCH 512
#define THREADS 1024
#define ROWLEN 257

typedef __attribute__((ext_vector_type(8))) short bf16x8;           // 8 bf16 (4 VGPRs)
typedef __attribute__((ext_vector_type(4))) float f32x4;            // MFMA C/D frag
typedef __attribute__((ext_vector_type(4))) unsigned short u16x4;   // 8B packed bf16
typedef float f4u __attribute__((ext_vector_type(4), aligned(4)));  // 4B-aligned float4 load

__device__ __forceinline__ unsigned short f2bf(float f) {       // RNE float->bf16
    unsigned u = __float_as_uint(f);
    u += 0x7FFFu + ((u >> 16) & 1u);
    return (unsigned short)(u >> 16);
}
__device__ __forceinline__ float bf2f(unsigned short h) {
    return __uint_as_float(((unsigned)h) << 16);
}
__device__ __forceinline__ float fast_ssp(float x) {            // softplus(x)-log2, stable
    return fmaxf(x, 0.f) + __logf(1.f + __expf(-fabsf(x))) - 0.69314718055994531f;
}
// XOR swizzle: row-major [128][256B] bf16 plane, byte ^= (row&7)<<4 -> row-strided
// b128/b64 accesses spread across 8 16B slots (<=2-way = free). Same map write & read.
__device__ __forceinline__ int swz(int row, int cbyte) {
    return row * 256 + (cbyte ^ ((row & 7) << 4));
}

// LDS plane byte offsets (4 x 32KB = 128KB dynamic)
#define PH 0        // act_x hi  -> X hi
#define PL 32768    // act_x lo  -> X lo
#define QH 65536    // act_k hi  -> K hi
#define QL 98304    // act_k lo  -> K lo

__global__ void wsplit_kernel(const float* __restrict__ Wx,
                              const float* __restrict__ Wk,
                              unsigned short* __restrict__ ws) {
    int g = blockIdx.x * 256 + threadIdx.x;          // 0..32767
    const float* src = (g < 16384) ? Wx : Wk;
    int idx = g & 16383;
    float v = src[idx];
    unsigned short h = f2bf(v);
    unsigned short l = f2bf(v - bf2f(h));
    int base = (g < 16384) ? 0 : 32768;
    ws[base + idx] = h;
    ws[base + 16384 + idx] = l;
}

__global__ void __launch_bounds__(THREADS, 1)
gen_actions_kernel(const float* __restrict__ kx,
                   const float* __restrict__ pos,
                   const float* __restrict__ mask,
                   const float* __restrict__ scale_ptr,
                   const float* __restrict__ evala,
                   const float* __restrict__ bx,
                   const float* __restrict__ bk,
                   const unsigned short* __restrict__ ws,
                   float* __restrict__ out)
{
    extern __shared__ char lds[];
    __shared__ float posXs[NATOM], posYs[NATOM], posZs[NATOM], lsBs[NATOM];
    __shared__ float amBs[NATOM * 3];
    __shared__ float redBs[2];
    __shared__ int   cntBs[2];

    const int b = blockIdx.x;
    const int t = threadIdx.x;
    const int lane = t & 63;
    const int w = t >> 6;            // wave 0..15
    const int wr = w >> 2;           // M tile (features / atoms-i), 0..3 (32 rows)
    const int wc = w & 3;            // N tile (atoms-j), 0..3 (32 cols)
    const int l15 = lane & 15;
    const int l4  = lane >> 4;

    // ---------------- P1: count, positions, zero accumulators
    if (t < NATOM) {
        float m = mask[b * NATOM + t];
        unsigned long long bal = __ballot(m > 0.5f);
        if ((t & 63) == 0) cntBs[t >> 6] = __popcll(bal);
        const float* p = pos + ((size_t)b * NATOM + t) * 3;
        posXs[t] = p[0]; posYs[t] = p[1]; posZs[t] = p[2];
    }
    if (t < NATOM * 3) amBs[t] = 0.f;
    __syncthreads();
    const int count = cntBs[0] + cntBs[1];   // mask is a contiguous prefix

    // ---------------- P2: activations -> hi/lo bf16 planes in LDS
    // 8 threads per atom row, 32 floats each: wave = 8 rows x 128B contiguous chunks.
    // Register-stage all 8 float4 loads first (latency overlap), then activate+pack.
    {
        const int i = t >> 3, q = t & 7;            // row, segment
        const float* row = kx + (size_t)b * (NATOM * ROWLEN) + i * ROWLEN + q * 32;
        const bool masked = (i >= count);
        f4u v[8];
        #pragma unroll
        for (int j4 = 0; j4 < 8; ++j4) v[j4] = *(const f4u*)(row + j4 * 4);
        float lstd = (q == 7) ? row[32] : 0.f;      // col 256 = log_std
        const bool isX = (q < 4);
        char* baseH = lds + (isX ? PH : QH);
        char* baseL = lds + (isX ? PL : QL);
        const int ebase = isX ? q * 32 : (q - 4) * 32;
        #pragma unroll
        for (int j4 = 0; j4 < 8; ++j4) {
            u16x4 hs, ls;
            #pragma unroll
            for (int c = 0; c < 4; ++c) {
                float x = masked ? 0.f : v[j4][c];
                float a = isX ? fast_ssp(x) : fmaxf(x, 0.f);
                unsigned short h = f2bf(a);
                hs[c] = h;
                ls[c] = f2bf(a - bf2f(h));
            }
            int cb = (ebase + j4 * 4) * 2;
            *(u16x4*)(baseH + swz(i, cb)) = hs;
            *(u16x4*)(baseL + swz(i, cb)) = ls;
        }
        if (q == 7) lsBs[i] = masked ? 0.f : lstd;
    }
    __syncthreads();

    // ---------------- P3: X = act @ W^T + b, computed as D[feature][atom]
    // split-bf16: X = Wh*Ah + Wl*Ah + Wh*Al  (drop Wl*Al, rel err ~2^-16)
    for (int mat = 0; mat < 2; ++mat) {
        char* actH = lds + (mat ? QH : PH);
        char* actL = lds + (mat ? QL : PL);
        const unsigned short* WH = ws + mat * 32768;
        const unsigned short* WL = WH + 16384;
        const float* bias = mat ? bk : bx;
        const int n0 = wc * 32;                    // atom tile base (N-dim)
        f32x4 acc[2][2] = {};
        if (n0 < count) {
            for (int ks = 0; ks < 4; ++ks) {
                const int e0 = ks * 32 + l4 * 8;   // k-offset for this lane
                bf16x8 wh[2], wl[2], ah[2], al[2];
                #pragma unroll
                for (int mf = 0; mf < 2; ++mf) {
                    int orow = wr * 32 + mf * 16 + l15;
                    wh[mf] = *(const bf16x8*)(WH + orow * 128 + e0);
                    wl[mf] = *(const bf16x8*)(WL + orow * 128 + e0);
                }
                #pragma unroll
                for (int nf = 0; nf < 2; ++nf) {
                    int jrow = n0 + nf * 16 + l15;
                    ah[nf] = *(const bf16x8*)(actH + swz(jrow, e0 * 2));
                    al[nf] = *(const bf16x8*)(actL + swz(jrow, e0 * 2));
                }
                #pragma unroll
                for (int mf = 0; mf < 2; ++mf)
                    #pragma unroll
                    for (int nf = 0; nf < 2; ++nf) {
                        acc[mf][nf] = __builtin_amdgcn_mfma_f32_16x16x32_bf16(wh[mf], ah[nf], acc[mf][nf], 0, 0, 0);
                        acc[mf][nf] = __builtin_amdgcn_mfma_f32_16x16x32_bf16(wl[mf], ah[nf], acc[mf][nf], 0, 0, 0);
                        acc[mf][nf] = __builtin_amdgcn_mfma_f32_16x16x32_bf16(wh[mf], al[nf], acc[mf][nf], 0, 0, 0);
                    }
            }
        }
        __syncthreads();      // all act reads complete before overwrite
        if (n0 < count) {
            #pragma unroll
            for (int mf = 0; mf < 2; ++mf) {
                int ob = wr * 32 + mf * 16 + l4 * 4;         // 4 consecutive features
                f32x4 b4 = *(const f32x4*)(bias + ob);
                #pragma unroll
                for (int nf = 0; nf < 2; ++nf) {
                    int jrow = n0 + nf * 16 + l15;           // atom (D col)
                    u16x4 hs, ls;
                    #pragma unroll
                    for (int r = 0; r < 4; ++r) {
                        float vv = acc[mf][nf][r] + b4[r];
                        unsigned short h = f2bf(vv);
                        hs[r] = h;
                        ls[r] = f2bf(vv - bf2f(h));
                    }
                    *(u16x4*)(actH + swz(jrow, ob * 2)) = hs;   // X[atom][o] hi
                    *(u16x4*)(actL + swz(jrow, ob * 2)) = ls;   // X[atom][o] lo
                }
            }
        }
        __syncthreads();
    }

    // ---------------- P4: Grams G = X@X^T, K@K^T (split-bf16) + pairwise epilogue
    const int m0g = wr * 32;       // i tile base
    const int n0g = wc * 32;       // j tile base
    f32x4 gx[2][2] = {}, gk[2][2] = {};
    const bool active = (m0g < count) && (n0g < count);
    if (active) {
        // X gram
        for (int ks = 0; ks < 4; ++ks) {
            const int e0b = (ks * 32 + l4 * 8) * 2;
            bf16x8 aH[2], aL[2], bH[2], bL[2];
            #pragma unroll
            for (int mf = 0; mf < 2; ++mf) {
                int irow = m0g + mf * 16 + l15;
                aH[mf] = *(const bf16x8*)(lds + PH + swz(irow, e0b));
                aL[mf] = *(const bf16x8*)(lds + PL + swz(irow, e0b));
            }
            #pragma unroll
            for (int nf = 0; nf < 2; ++nf) {
                int jrow = n0g + nf * 16 + l15;
                bH[nf] = *(const bf16x8*)(lds + PH + swz(jrow, e0b));
                bL[nf] = *(const bf16x8*)(lds + PL + swz(jrow, e0b));
            }
            #pragma unroll
            for (int mf = 0; mf < 2; ++mf)
                #pragma unroll
                for (int nf = 0; nf < 2; ++nf) {
                    gx[mf][nf] = __builtin_amdgcn_mfma_f32_16x16x32_bf16(aH[mf], bH[nf], gx[mf][nf], 0, 0, 0);
                    gx[mf][nf] = __builtin_amdgcn_mfma_f32_16x16x32_bf16(aH[mf], bL[nf], gx[mf][nf], 0, 0, 0);
                    gx[mf][nf] = __builtin_amdgcn_mfma_f32_16x16x32_bf16(aL[mf], bH[nf], gx[mf][nf], 0, 0, 0);
                }
        }
        // K gram
        for (int ks = 0; ks < 4; ++ks) {
            const int e0b = (ks * 32 + l4 * 8) * 2;
            bf16x8 aH[2], aL[2], bH[2], bL[2];
            #pragma unroll
            for (int mf = 0; mf < 2; ++mf) {
                int irow = m0g + mf * 16 + l15;
                aH[mf] = *(const bf16x8*)(lds + QH + swz(irow, e0b));
                aL[mf] = *(const bf16x8*)(lds + QL + swz(irow, e0b));
            }
            #pragma unroll
            for (int nf = 0; nf < 2; ++nf) {
                int jrow = n0g + nf * 16 + l15;
                bH[nf] = *(const bf16x8*)(lds + QH + swz(jrow, e0b));
                bL[nf] = *(const bf16x8*)(lds + QL + swz(jrow, e0b));
            }
            #pragma unroll
            for (int mf = 0; mf < 2; ++mf)
                #pragma unroll
                for (int nf = 0; nf < 2; ++nf) {
                    gk[mf][nf] = __builtin_amdgcn_mfma_f32_16x16x32_bf16(aH[mf], bH[nf], gk[mf][nf], 0, 0, 0);
                    gk[mf][nf] = __builtin_amdgcn_mfma_f32_16x16x32_bf16(aH[mf], bL[nf], gk[mf][nf], 0, 0, 0);
                    gk[mf][nf] = __builtin_amdgcn_mfma_f32_16x16x32_bf16(aL[mf], bH[nf], gk[mf][nf], 0, 0, 0);
                }
        }
        // pairwise epilogue directly on D-frags: lane column j fixed per nf
        const float inv_e = 0.08838834764831845f;            // 1/sqrt(128)
        #pragma unroll
        for (int nf = 0; nf < 2; ++nf) {
            const int j = n0g + nf * 16 + l15;
            const bool jvalid = (j < count);
            const float pjx = posXs[j], pjy = posYs[j], pjz = posZs[j];
            float amx = 0.f, amy = 0.f, amz = 0.f;
            #pragma unroll
            for (int mf = 0; mf < 2; ++mf) {
                #pragma unroll
                for (int r = 0; r < 4; ++r) {
                    const int i = m0g + mf * 16 + l4 * 4 + r;
                    float dx = pjx - posXs[i];
                    float dy = pjy - posYs[i];
                    float dz = pjz - posZs[i];
                    float r2 = fmaf(dx, dx, fmaf(dy, dy, dz * dz)) + 1e-16f;
                    float rr = sqrtf(r2);
                    bool ok = jvalid && (i < count) && (rr < 5.0f);
                    float fc = ok ? (0.5f * (__cosf(rr * 0.62831853071795865f) + 1.f)) : 0.f;
                    float xs = fmaf(gx[mf][nf][r], -0.044194173824159216f, rr * 0.5f);
                    float fv = xs * (gk[mf][nf][r] * inv_e) * fc;
                    float wgt = fv / (rr + 1e-8f);
                    amx = fmaf(dx, wgt, amx);
                    amy = fmaf(dy, wgt, amy);
                    amz = fmaf(dz, wgt, amz);
                }
            }
            amx += __shfl_xor(amx, 16); amx += __shfl_xor(amx, 32);
            amy += __shfl_xor(amy, 16); amy += __shfl_xor(amy, 32);
            amz += __shfl_xor(amz, 16); amz += __shfl_xor(amz, 32);
            if (l4 == 0 && jvalid) {
                atomicAdd(&amBs[j * 3 + 0], amx);
                atomicAdd(&amBs[j * 3 + 1], amy);
                atomicAdd(&amBs[j * 3 + 2], amz);
            }
        }
    }
    __syncthreads();

    // ---------------- P5: outputs
    if (t < 96) {
        f32x4 ev4 = *(const f32x4*)(evala + (size_t)b * 384 + t * 4);
        f32x4 o4;
        #pragma unroll
        for (int c = 0; c < 4; ++c) {
            int atom = (t * 4 + c) / 3;
            o4[c] = (atom < count) ? ev4[c] : 0.f;
        }
        *(f32x4*)(out + (size_t)b * 384 + t * 4) = o4;
    }
    float lp = 0.f;
    if (t < NATOM && t < count) {
        const int j = t;
        const float* ev = evala + ((size_t)b * NATOM + j) * 3;
        float e0v = ev[0], e1v = ev[1], e2v = ev[2];
        float scale = scale_ptr[0];
        float ax = amBs[j * 3 + 0], ay = amBs[j * 3 + 1], az = amBs[j * 3 + 2];
        float nrm = sqrtf(fmaf(ax, ax, fmaf(ay, ay, az * az)) + 1e-16f) + 1e-8f;
        float qe = __expf(-2.f * nrm);
        float th = (1.f - qe) / (1.f + qe);
        float sc = th / nrm * scale;
        float mux = ax * sc, muy = ay * sc, muz = az * sc;
        float ls = fminf(fmaxf(lsBs[j], -20.f), 2.f);
        float sig = __expf(ls) * scale;
        float sinv = 1.f / sig;
        float lsg = __logf(sig);
        float zx = (e0v - mux) * sinv;
        float zy = (e1v - muy) * sinv;
        float zz = (e2v - muz) * sinv;
        lp = -0.5f * (zx * zx + zy * zy + zz * zz) - 3.f * lsg
             - 3.f * 0.91893853320467274f;
    }
    #pragma unroll
    for (int off = 32; off > 0; off >>= 1) lp += __shfl_down(lp, off);
    if (t == 0)  redBs[0] = lp;
    if (t == 64) redBs[1] = lp;
    __syncthreads();
    if (t == 0) out[(size_t)NBATCH * NATOM * 3 + b] = redBs[0] + redBs[1];
}

extern "C" void kernel_launch(void* const* d_in, const int* in_sizes, int n_in,
                              void* d_out, int out_size, void* d_ws, size_t ws_size,
                              hipStream_t stream) {
    const float* kx    = (const float*)d_in[0];
    const float* pos   = (const float*)d_in[1];
    const float* mask  = (const float*)d_in[2];
    const float* scale = (const float*)d_in[3];
    const float* ev    = (const float*)d_in[4];
    const float* Wx    = (const float*)d_in[5];
    const float* bx    = (const float*)d_in[6];
    const float* Wk    = (const float*)d_in[7];
    const float* bk    = (const float*)d_in[8];
    float* out = (float*)d_out;
    unsigned short* ws = (unsigned short*)d_ws;

    // W hi/lo split (128KB in d_ws), recomputed each launch (deterministic)
    hipLaunchKernelGGL(wsplit_kernel, dim3(128), dim3(256), 0, stream, Wx, Wk, ws);

    const size_t shbytes = 131072;   // 4 planes x 32KB dynamic LDS
    (void)hipFuncSetAttribute((const void*)gen_actions_kernel,
                              hipFuncAttributeMaxDynamicSharedMemorySize,
                              (int)shbytes);
    hipLaunchKernelGGL(gen_actions_kernel, dim3(NBATCH), dim3(THREADS), shbytes, stream,
                       kx, pos, mask, scale, ev, bx, bk, ws, out);
}

// Round 4
// 73.520 us; speedup vs baseline: 3.0770x; 1.1157x over previous
//
#include <hip/hip_runtime.h>
#include <math.h>

#define EDIM 128
#define NATOM 128
#define NBATCH 512
#define THREADS 1024
#define ROWLEN 257

typedef __attribute__((ext_vector_type(8))) short bf16x8;           // 8 bf16 (4 VGPRs)
typedef __attribute__((ext_vector_type(4))) float f32x4;            // MFMA C/D frag
typedef __attribute__((ext_vector_type(4))) unsigned short u16x4;   // 8B packed bf16
typedef float f4u __attribute__((ext_vector_type(4), aligned(4)));  // element-aligned float4

__device__ __forceinline__ unsigned short f2bf(float f) {       // RNE float->bf16
    unsigned u = __float_as_uint(f);
    u += 0x7FFFu + ((u >> 16) & 1u);
    return (unsigned short)(u >> 16);
}
__device__ __forceinline__ float bf2f(unsigned short h) {
    return __uint_as_float(((unsigned)h) << 16);
}
__device__ __forceinline__ float fast_ssp(float x) {            // softplus(x)-log2, stable
    return fmaxf(x, 0.f) + __logf(1.f + __expf(-fabsf(x))) - 0.69314718055994531f;
}
// XOR swizzle: row-major [128][256B] bf16 plane; phase=64 for K/Q planes so that
// P2's paired X/K stores (same (row,col), different plane) hit disjoint bank-pairs.
__device__ __forceinline__ int swzp(int row, int cbyte, int phase) {
    return row * 256 + (cbyte ^ ((row & 7) << 4) ^ phase);
}

// LDS plane byte offsets (2 x 32KB = 64KB dynamic -> 2 blocks/CU)
#define PH 0        // act_x -> X   (phase 0)
#define QH 32768    // act_k -> K   (phase 64)

__global__ void wsplit_kernel(const float* __restrict__ Wx,
                              const float* __restrict__ Wk,
                              unsigned short* __restrict__ ws) {
    int g = blockIdx.x * 256 + threadIdx.x;          // 0..32767
    const float* src = (g < 16384) ? Wx : Wk;
    int idx = g & 16383;
    float v = src[idx];
    unsigned short h = f2bf(v);
    unsigned short l = f2bf(v - bf2f(h));
    int base = (g < 16384) ? 0 : 32768;
    ws[base + idx] = h;
    ws[base + 16384 + idx] = l;
}

__global__ void __launch_bounds__(THREADS, 2)
gen_actions_kernel(const float* __restrict__ kx,
                   const float* __restrict__ pos,
                   const float* __restrict__ mask,
                   const float* __restrict__ scale_ptr,
                   const float* __restrict__ evala,
                   const float* __restrict__ bx,
                   const float* __restrict__ bk,
                   const unsigned short* __restrict__ ws,
                   float* __restrict__ out)
{
    extern __shared__ char lds[];
    __shared__ float posXs[NATOM], posYs[NATOM], posZs[NATOM], lsBs[NATOM];
    __shared__ float amBs[NATOM * 3];
    __shared__ float redBs[2];
    __shared__ int   cntBs[2];

    const int b = blockIdx.x;
    const int t = threadIdx.x;
    const int lane = t & 63;
    const int w = t >> 6;            // wave 0..15
    const int wr = w >> 2;           // M tile (features / atoms-i), 0..3
    const int wc = w & 3;            // N tile (atoms-j), 0..3
    const int l15 = lane & 15;
    const int l4  = lane >> 4;

    // ---------------- P1: count, positions, zero accumulators
    if (t < NATOM) {
        float m = mask[b * NATOM + t];
        unsigned long long bal = __ballot(m > 0.5f);
        if ((t & 63) == 0) cntBs[t >> 6] = __popcll(bal);
        const float* p = pos + ((size_t)b * NATOM + t) * 3;
        posXs[t] = p[0]; posYs[t] = p[1]; posZs[t] = p[2];
    }
    if (t < NATOM * 3) amBs[t] = 0.f;
    __syncthreads();
    const int count = cntBs[0] + cntBs[1];   // mask is a contiguous prefix

    // ---------------- P2: activations -> bf16 planes (8 threads/row, 32 floats each)
    {
        const int i = t >> 3, q = t & 7;
        const bool isX = (q < 4);
        char* base = lds + (isX ? PH : QH);
        const int phase = isX ? 0 : 64;
        const int ebase = (q & 3) * 32;
        if (i >= count) {                    // masked rows: write zeros, skip loads+math
            u16x4 z = (u16x4)0;
            #pragma unroll
            for (int j4 = 0; j4 < 8; ++j4)
                *(u16x4*)(base + swzp(i, (ebase + j4 * 4) * 2, phase)) = z;
            if (q == 7) lsBs[i] = 0.f;
        } else {
            const float* row = kx + (size_t)b * (NATOM * ROWLEN) + i * ROWLEN + q * 32;
            f4u v[8];
            #pragma unroll
            for (int j4 = 0; j4 < 8; ++j4) v[j4] = *(const f4u*)(row + j4 * 4);
            float lstd = (q == 7) ? row[32] : 0.f;      // col 256 = log_std
            #pragma unroll
            for (int j4 = 0; j4 < 8; ++j4) {
                u16x4 hs;
                #pragma unroll
                for (int c = 0; c < 4; ++c) {
                    float a = isX ? fast_ssp(v[j4][c]) : fmaxf(v[j4][c], 0.f);
                    hs[c] = f2bf(a);
                }
                *(u16x4*)(base + swzp(i, (ebase + j4 * 4) * 2, phase)) = hs;
            }
            if (q == 7) lsBs[i] = lstd;
        }
    }
    __syncthreads();

    // ---------------- P3: X = act @ W^T + b as D[feature][atom]; W hi/lo split
    // (free accuracy: X = Wh*A + Wl*A, W split precomputed in d_ws, L2-resident)
    for (int mat = 0; mat < 2; ++mat) {
        char* act = lds + (mat ? QH : PH);
        const int phase = mat ? 64 : 0;
        const unsigned short* WH = ws + mat * 32768;
        const unsigned short* WL = WH + 16384;
        const float* bias = mat ? bk : bx;
        const int n0 = wc * 32;                    // atom tile base (N-dim)
        f32x4 acc[2][2] = {};
        if (n0 < count) {
            for (int ks = 0; ks < 4; ++ks) {
                const int e0 = ks * 32 + l4 * 8;   // k-offset for this lane
                bf16x8 wh[2], wl[2], ah[2];
                #pragma unroll
                for (int mf = 0; mf < 2; ++mf) {
                    int orow = wr * 32 + mf * 16 + l15;
                    wh[mf] = *(const bf16x8*)(WH + orow * 128 + e0);
                    wl[mf] = *(const bf16x8*)(WL + orow * 128 + e0);
                }
                #pragma unroll
                for (int nf = 0; nf < 2; ++nf) {
                    int jrow = n0 + nf * 16 + l15;
                    ah[nf] = *(const bf16x8*)(act + swzp(jrow, e0 * 2, phase));
                }
                #pragma unroll
                for (int mf = 0; mf < 2; ++mf)
                    #pragma unroll
                    for (int nf = 0; nf < 2; ++nf) {
                        acc[mf][nf] = __builtin_amdgcn_mfma_f32_16x16x32_bf16(wh[mf], ah[nf], acc[mf][nf], 0, 0, 0);
                        acc[mf][nf] = __builtin_amdgcn_mfma_f32_16x16x32_bf16(wl[mf], ah[nf], acc[mf][nf], 0, 0, 0);
                    }
            }
        }
        __syncthreads();      // all act reads complete before overwrite
        if (n0 < count) {
            #pragma unroll
            for (int mf = 0; mf < 2; ++mf) {
                int ob = wr * 32 + mf * 16 + l4 * 4;         // 4 consecutive features
                f32x4 b4 = *(const f32x4*)(bias + ob);
                #pragma unroll
                for (int nf = 0; nf < 2; ++nf) {
                    int jrow = n0 + nf * 16 + l15;           // atom (D col)
                    u16x4 hs;
                    #pragma unroll
                    for (int r = 0; r < 4; ++r) hs[r] = f2bf(acc[mf][nf][r] + b4[r]);
                    *(u16x4*)(act + swzp(jrow, ob * 2, phase)) = hs;  // X[atom][feat]
                }
            }
        }
        __syncthreads();
    }

    // ---------------- P4: Grams G = X@X^T, K@K^T (bf16) + pairwise epilogue
    const int m0g = wr * 32;       // i tile base
    const int n0g = wc * 32;       // j tile base
    f32x4 gx[2][2] = {}, gk[2][2] = {};
    const bool active = (m0g < count) && (n0g < count);
    if (active) {
        for (int ks = 0; ks < 4; ++ks) {           // X gram
            const int e0b = (ks * 32 + l4 * 8) * 2;
            bf16x8 aH[2], bH[2];
            #pragma unroll
            for (int mf = 0; mf < 2; ++mf)
                aH[mf] = *(const bf16x8*)(lds + PH + swzp(m0g + mf * 16 + l15, e0b, 0));
            #pragma unroll
            for (int nf = 0; nf < 2; ++nf)
                bH[nf] = *(const bf16x8*)(lds + PH + swzp(n0g + nf * 16 + l15, e0b, 0));
            #pragma unroll
            for (int mf = 0; mf < 2; ++mf)
                #pragma unroll
                for (int nf = 0; nf < 2; ++nf)
                    gx[mf][nf] = __builtin_amdgcn_mfma_f32_16x16x32_bf16(aH[mf], bH[nf], gx[mf][nf], 0, 0, 0);
        }
        for (int ks = 0; ks < 4; ++ks) {           // K gram
            const int e0b = (ks * 32 + l4 * 8) * 2;
            bf16x8 aH[2], bH[2];
            #pragma unroll
            for (int mf = 0; mf < 2; ++mf)
                aH[mf] = *(const bf16x8*)(lds + QH + swzp(m0g + mf * 16 + l15, e0b, 64));
            #pragma unroll
            for (int nf = 0; nf < 2; ++nf)
                bH[nf] = *(const bf16x8*)(lds + QH + swzp(n0g + nf * 16 + l15, e0b, 64));
            #pragma unroll
            for (int mf = 0; mf < 2; ++mf)
                #pragma unroll
                for (int nf = 0; nf < 2; ++nf)
                    gk[mf][nf] = __builtin_amdgcn_mfma_f32_16x16x32_bf16(aH[mf], bH[nf], gk[mf][nf], 0, 0, 0);
        }
        // pairwise epilogue on D-frags: lane's column j fixed per nf
        const float inv_e = 0.08838834764831845f;            // 1/sqrt(128)
        #pragma unroll
        for (int nf = 0; nf < 2; ++nf) {
            const int j = n0g + nf * 16 + l15;
            const bool jvalid = (j < count);
            const float pjx = posXs[j], pjy = posYs[j], pjz = posZs[j];
            float amx = 0.f, amy = 0.f, amz = 0.f;
            #pragma unroll
            for (int mf = 0; mf < 2; ++mf) {
                #pragma unroll
                for (int r = 0; r < 4; ++r) {
                    const int i = m0g + mf * 16 + l4 * 4 + r;
                    float dx = pjx - posXs[i];
                    float dy = pjy - posYs[i];
                    float dz = pjz - posZs[i];
                    float r2 = fmaf(dx, dx, fmaf(dy, dy, dz * dz)) + 1e-16f;
                    float rr = sqrtf(r2);
                    bool ok = jvalid && (i < count) && (rr < 5.0f);
                    float fc = ok ? (0.5f * (__cosf(rr * 0.62831853071795865f) + 1.f)) : 0.f;
                    float xs = fmaf(gx[mf][nf][r], -0.044194173824159216f, rr * 0.5f);
                    float fv = xs * (gk[mf][nf][r] * inv_e) * fc;
                    float wgt = fv / (rr + 1e-8f);
                    amx = fmaf(dx, wgt, amx);
                    amy = fmaf(dy, wgt, amy);
                    amz = fmaf(dz, wgt, amz);
                }
            }
            amx += __shfl_xor(amx, 16); amx += __shfl_xor(amx, 32);
            amy += __shfl_xor(amy, 16); amy += __shfl_xor(amy, 32);
            amz += __shfl_xor(amz, 16); amz += __shfl_xor(amz, 32);
            if (l4 == 0 && jvalid) {
                atomicAdd(&amBs[j * 3 + 0], amx);
                atomicAdd(&amBs[j * 3 + 1], amy);
                atomicAdd(&amBs[j * 3 + 2], amz);
            }
        }
    }
    __syncthreads();

    // ---------------- P5: outputs
    if (t < 96) {
        f32x4 ev4 = *(const f32x4*)(evala + (size_t)b * 384 + t * 4);
        f32x4 o4;
        #pragma unroll
        for (int c = 0; c < 4; ++c) {
            int atom = (t * 4 + c) / 3;
            o4[c] = (atom < count) ? ev4[c] : 0.f;
        }
        *(f32x4*)(out + (size_t)b * 384 + t * 4) = o4;
    }
    float lp = 0.f;
    if (t < NATOM && t < count) {
        const int j = t;
        const float* ev = evala + ((size_t)b * NATOM + j) * 3;
        float e0v = ev[0], e1v = ev[1], e2v = ev[2];
        float scale = scale_ptr[0];
        float ax = amBs[j * 3 + 0], ay = amBs[j * 3 + 1], az = amBs[j * 3 + 2];
        float nrm = sqrtf(fmaf(ax, ax, fmaf(ay, ay, az * az)) + 1e-16f) + 1e-8f;
        float qe = __expf(-2.f * nrm);
        float th = (1.f - qe) / (1.f + qe);
        float sc = th / nrm * scale;
        float mux = ax * sc, muy = ay * sc, muz = az * sc;
        float ls = fminf(fmaxf(lsBs[j], -20.f), 2.f);
        float sig = __expf(ls) * scale;
        float sinv = 1.f / sig;
        float lsg = __logf(sig);
        float zx = (e0v - mux) * sinv;
        float zy = (e1v - muy) * sinv;
        float zz = (e2v - muz) * sinv;
        lp = -0.5f * (zx * zx + zy * zy + zz * zz) - 3.f * lsg
             - 3.f * 0.91893853320467274f;
    }
    #pragma unroll
    for (int off = 32; off > 0; off >>= 1) lp += __shfl_down(lp, off);
    if (t == 0)  redBs[0] = lp;
    if (t == 64) redBs[1] = lp;
    __syncthreads();
    if (t == 0) out[(size_t)NBATCH * NATOM * 3 + b] = redBs[0] + redBs[1];
}

extern "C" void kernel_launch(void* const* d_in, const int* in_sizes, int n_in,
                              void* d_out, int out_size, void* d_ws, size_t ws_size,
                              hipStream_t stream) {
    const float* kx    = (const float*)d_in[0];
    const float* pos   = (const float*)d_in[1];
    const float* mask  = (const float*)d_in[2];
    const float* scale = (const float*)d_in[3];
    const float* ev    = (const float*)d_in[4];
    const float* Wx    = (const float*)d_in[5];
    const float* bx    = (const float*)d_in[6];
    const float* Wk    = (const float*)d_in[7];
    const float* bk    = (const float*)d_in[8];
    float* out = (float*)d_out;
    unsigned short* ws = (unsigned short*)d_ws;

    // W hi/lo split (128KB in d_ws), recomputed each launch (deterministic)
    hipLaunchKernelGGL(wsplit_kernel, dim3(128), dim3(256), 0, stream, Wx, Wk, ws);

    const size_t shbytes = 65536;   // 2 planes x 32KB dynamic LDS -> 2 blocks/CU
    (void)hipFuncSetAttribute((const void*)gen_actions_kernel,
                              hipFuncAttributeMaxDynamicSharedMemorySize,
                              (int)shbytes);
    hipLaunchKernelGGL(gen_actions_kernel, dim3(NBATCH), dim3(THREADS), shbytes, stream,
                       kx, pos, mask, scale, ev, bx, bk, ws, out);
}

// Round 5
// 67.000 us; speedup vs baseline: 3.3764x; 1.0973x over previous
//
#include <hip/hip_runtime.h>
#include <math.h>

#define EDIM 128
#define NATOM 128
#define NBATCH 512
#define THREADS 1024
#define ROWLEN 257

typedef __attribute__((ext_vector_type(8))) short bf16x8;           // 8 bf16 (4 VGPRs)
typedef __attribute__((ext_vector_type(4))) float f32x4;            // MFMA C/D frag
typedef __attribute__((ext_vector_type(4))) unsigned short u16x4;   // 8B packed bf16
typedef float f4u __attribute__((ext_vector_type(4), aligned(4)));  // element-aligned float4

__device__ __forceinline__ unsigned short f2bf(float f) {       // RNE float->bf16
    unsigned u = __float_as_uint(f);
    u += 0x7FFFu + ((u >> 16) & 1u);
    return (unsigned short)(u >> 16);
}
__device__ __forceinline__ float bf2f(unsigned short h) {
    return __uint_as_float(((unsigned)h) << 16);
}
__device__ __forceinline__ float fast_ssp(float x) {            // softplus(x)-log2, stable
    return fmaxf(x, 0.f) + __logf(1.f + __expf(-fabsf(x))) - 0.69314718055994531f;
}
// XOR swizzle: row-major [128][256B] bf16 plane; phase=64 decorrelates the K plane
// so P2's paired X/K stores (same row/col, different plane) hit different banks.
__device__ __forceinline__ int swzp(int row, int cbyte, int phase) {
    return row * 256 + ((cbyte ^ phase) ^ ((row & 7) << 4));
}

// LDS plane byte offsets (2 x 32KB = 64KB dynamic -> 2 blocks/CU)
#define PH 0        // act_x -> X   (phase 0)
#define QH 32768    // act_k -> K   (phase 64)

__global__ void wsplit_kernel(const float* __restrict__ Wx,
                              const float* __restrict__ Wk,
                              unsigned short* __restrict__ ws) {
    int g = blockIdx.x * 256 + threadIdx.x;          // 0..32767
    const float* src = (g < 16384) ? Wx : Wk;
    int idx = g & 16383;
    float v = src[idx];
    unsigned short h = f2bf(v);
    unsigned short l = f2bf(v - bf2f(h));
    int base = (g < 16384) ? 0 : 32768;
    ws[base + idx] = h;
    ws[base + 16384 + idx] = l;
}

__global__ void __launch_bounds__(THREADS, 8)   // 8 waves/EU -> 2 blocks/CU, VGPR<=64
gen_actions_kernel(const float* __restrict__ kx,
                   const float* __restrict__ pos,
                   const float* __restrict__ mask,
                   const float* __restrict__ scale_ptr,
                   const float* __restrict__ evala,
                   const float* __restrict__ bx,
                   const float* __restrict__ bk,
                   const unsigned short* __restrict__ ws,
                   float* __restrict__ out)
{
    extern __shared__ char lds[];
    __shared__ float posXs[NATOM], posYs[NATOM], posZs[NATOM], lsBs[NATOM];
    __shared__ float amBs[NATOM * 3];
    __shared__ float redBs[2];
    __shared__ int   cntBs[2];

    const int b = blockIdx.x;
    const int t = threadIdx.x;
    const int lane = t & 63;
    const int w = t >> 6;            // wave 0..15
    const int wr = w >> 2;           // M tile (features / atoms-i), 0..3
    const int wc = w & 3;            // N tile (atoms-j), 0..3
    const int l15 = lane & 15;
    const int l4  = lane >> 4;

    // ---------------- entry: UNCONDITIONAL kx prefetch (issues before anything else).
    // Masked rows need no zeroing: every masked contribution is killed downstream
    // (ok-guard in P4, t<count gates in P5), so activations may hold garbage there.
    const int pi = t >> 3, pq = t & 7;            // row, 32-float segment
    const float* prow = kx + (size_t)b * (NATOM * ROWLEN) + pi * ROWLEN + pq * 32;
    f4u v[8];
    #pragma unroll
    for (int j4 = 0; j4 < 8; ++j4) v[j4] = *(const f4u*)(prow + j4 * 4);
    float lstd = (pq == 7) ? prow[32] : 0.f;      // col 256 = log_std

    // ---------------- P1 (overlaps kx loads): count, positions, zero accumulators
    if (t < NATOM) {
        float m = mask[b * NATOM + t];
        unsigned long long bal = __ballot(m > 0.5f);
        if ((t & 63) == 0) cntBs[t >> 6] = __popcll(bal);
        const float* p = pos + ((size_t)b * NATOM + t) * 3;
        posXs[t] = p[0]; posYs[t] = p[1]; posZs[t] = p[2];
    }
    if (t < NATOM * 3) amBs[t] = 0.f;

    // ---------------- P2: activations -> bf16 planes (8 threads/row, no masking)
    {
        const bool isX = (pq < 4);
        char* base = lds + (isX ? PH : QH);
        const int phase = isX ? 0 : 64;
        const int ebase = (pq & 3) * 32;
        #pragma unroll
        for (int j4 = 0; j4 < 8; ++j4) {
            u16x4 hs;
            #pragma unroll
            for (int c = 0; c < 4; ++c) {
                float a = isX ? fast_ssp(v[j4][c]) : fmaxf(v[j4][c], 0.f);
                hs[c] = f2bf(a);
            }
            *(u16x4*)(base + swzp(pi, (ebase + j4 * 4) * 2, phase)) = hs;
        }
        if (pq == 7) lsBs[pi] = lstd;
    }
    __syncthreads();                 // B1: planes + count + pos + amBs all ready
    const int count = cntBs[0] + cntBs[1];   // mask is a contiguous prefix

    // ---------------- P3 (merged): X and K GEMMs in ONE barrier phase.
    // Each wave: mat0 MFMA -> pack bf16 to regs, mat1 MFMA -> pack, then barrier,
    // then both writes. W hi/lo split from d_ws (L2-hot) for ~fp32 accuracy.
    const int n0 = wc * 32;                    // atom tile base (N-dim)
    const bool nact = (n0 < count);
    u16x4 xpk[2][2], kpk[2][2];
    if (nact) {
        #pragma unroll
        for (int mat = 0; mat < 2; ++mat) {
            char* act = lds + (mat ? QH : PH);
            const int phase = mat ? 64 : 0;
            const unsigned short* WH = ws + mat * 32768;
            const unsigned short* WL = WH + 16384;
            const float* bias = mat ? bk : bx;
            f32x4 acc[2][2] = {};
            for (int ks = 0; ks < 4; ++ks) {
                const int e0 = ks * 32 + l4 * 8;   // k-offset for this lane
                bf16x8 wh[2], wl[2], ah[2];
                #pragma unroll
                for (int mf = 0; mf < 2; ++mf) {
                    int orow = wr * 32 + mf * 16 + l15;
                    wh[mf] = *(const bf16x8*)(WH + orow * 128 + e0);
                    wl[mf] = *(const bf16x8*)(WL + orow * 128 + e0);
                }
                #pragma unroll
                for (int nf = 0; nf < 2; ++nf) {
                    int jrow = n0 + nf * 16 + l15;
                    ah[nf] = *(const bf16x8*)(act + swzp(jrow, e0 * 2, phase));
                }
                #pragma unroll
                for (int mf = 0; mf < 2; ++mf)
                    #pragma unroll
                    for (int nf = 0; nf < 2; ++nf) {
                        acc[mf][nf] = __builtin_amdgcn_mfma_f32_16x16x32_bf16(wh[mf], ah[nf], acc[mf][nf], 0, 0, 0);
                        acc[mf][nf] = __builtin_amdgcn_mfma_f32_16x16x32_bf16(wl[mf], ah[nf], acc[mf][nf], 0, 0, 0);
                    }
            }
            #pragma unroll
            for (int mf = 0; mf < 2; ++mf) {
                int ob = wr * 32 + mf * 16 + l4 * 4;
                f32x4 b4 = *(const f32x4*)(bias + ob);
                #pragma unroll
                for (int nf = 0; nf < 2; ++nf) {
                    u16x4 hs;
                    #pragma unroll
                    for (int r = 0; r < 4; ++r) hs[r] = f2bf(acc[mf][nf][r] + b4[r]);
                    if (mat) kpk[mf][nf] = hs; else xpk[mf][nf] = hs;
                }
            }
        }
    }
    __syncthreads();                 // B2: all activation-plane reads complete
    if (nact) {
        #pragma unroll
        for (int mf = 0; mf < 2; ++mf) {
            int ob2 = (wr * 32 + mf * 16 + l4 * 4) * 2;
            #pragma unroll
            for (int nf = 0; nf < 2; ++nf) {
                int jrow = n0 + nf * 16 + l15;               // atom (D col)
                *(u16x4*)(lds + PH + swzp(jrow, ob2, 0))  = xpk[mf][nf];
                *(u16x4*)(lds + QH + swzp(jrow, ob2, 64)) = kpk[mf][nf];
            }
        }
    }
    __syncthreads();                 // B3: X,K planes ready

    // ---------------- P4: Grams G = X@X^T, K@K^T (bf16) + pairwise epilogue
    const int m0g = wr * 32;       // i tile base
    const int n0g = wc * 32;       // j tile base
    f32x4 gx[2][2] = {}, gk[2][2] = {};
    const bool active = (m0g < count) && (n0g < count);
    if (active) {
        for (int ks = 0; ks < 4; ++ks) {           // X gram
            const int e0b = (ks * 32 + l4 * 8) * 2;
            bf16x8 aH[2], bH[2];
            #pragma unroll
            for (int mf = 0; mf < 2; ++mf)
                aH[mf] = *(const bf16x8*)(lds + PH + swzp(m0g + mf * 16 + l15, e0b, 0));
            #pragma unroll
            for (int nf = 0; nf < 2; ++nf)
                bH[nf] = *(const bf16x8*)(lds + PH + swzp(n0g + nf * 16 + l15, e0b, 0));
            #pragma unroll
            for (int mf = 0; mf < 2; ++mf)
                #pragma unroll
                for (int nf = 0; nf < 2; ++nf)
                    gx[mf][nf] = __builtin_amdgcn_mfma_f32_16x16x32_bf16(aH[mf], bH[nf], gx[mf][nf], 0, 0, 0);
        }
        for (int ks = 0; ks < 4; ++ks) {           // K gram
            const int e0b = (ks * 32 + l4 * 8) * 2;
            bf16x8 aH[2], bH[2];
            #pragma unroll
            for (int mf = 0; mf < 2; ++mf)
                aH[mf] = *(const bf16x8*)(lds + QH + swzp(m0g + mf * 16 + l15, e0b, 64));
            #pragma unroll
            for (int nf = 0; nf < 2; ++nf)
                bH[nf] = *(const bf16x8*)(lds + QH + swzp(n0g + nf * 16 + l15, e0b, 64));
            #pragma unroll
            for (int mf = 0; mf < 2; ++mf)
                #pragma unroll
                for (int nf = 0; nf < 2; ++nf)
                    gk[mf][nf] = __builtin_amdgcn_mfma_f32_16x16x32_bf16(aH[mf], bH[nf], gk[mf][nf], 0, 0, 0);
        }
        // pairwise epilogue on D-frags: lane's column j fixed per nf
        const float inv_e = 0.08838834764831845f;            // 1/sqrt(128)
        #pragma unroll
        for (int nf = 0; nf < 2; ++nf) {
            const int j = n0g + nf * 16 + l15;
            const bool jvalid = (j < count);
            const float pjx = posXs[j], pjy = posYs[j], pjz = posZs[j];
            float amx = 0.f, amy = 0.f, amz = 0.f;
            #pragma unroll
            for (int mf = 0; mf < 2; ++mf) {
                #pragma unroll
                for (int r = 0; r < 4; ++r) {
                    const int i = m0g + mf * 16 + l4 * 4 + r;
                    float dx = pjx - posXs[i];
                    float dy = pjy - posYs[i];
                    float dz = pjz - posZs[i];
                    float r2 = fmaf(dx, dx, fmaf(dy, dy, dz * dz)) + 1e-16f;
                    float rr = sqrtf(r2);
                    bool ok = jvalid && (i < count) && (rr < 5.0f);
                    float fc = ok ? (0.5f * (__cosf(rr * 0.62831853071795865f) + 1.f)) : 0.f;
                    float xs = fmaf(gx[mf][nf][r], -0.044194173824159216f, rr * 0.5f);
                    float fv = xs * (gk[mf][nf][r] * inv_e) * fc;
                    float wgt = fv / (rr + 1e-8f);
                    amx = fmaf(dx, wgt, amx);
                    amy = fmaf(dy, wgt, amy);
                    amz = fmaf(dz, wgt, amz);
                }
            }
            amx += __shfl_xor(amx, 16); amx += __shfl_xor(amx, 32);
            amy += __shfl_xor(amy, 16); amy += __shfl_xor(amy, 32);
            amz += __shfl_xor(amz, 16); amz += __shfl_xor(amz, 32);
            if (l4 == 0 && jvalid) {
                atomicAdd(&amBs[j * 3 + 0], amx);
                atomicAdd(&amBs[j * 3 + 1], amy);
                atomicAdd(&amBs[j * 3 + 2], amz);
            }
        }
    }
    __syncthreads();                 // B4: actions_mean complete

    // ---------------- P5: outputs
    if (t < 96) {
        f32x4 ev4 = *(const f32x4*)(evala + (size_t)b * 384 + t * 4);
        f32x4 o4;
        #pragma unroll
        for (int c = 0; c < 4; ++c) {
            int atom = (t * 4 + c) / 3;
            o4[c] = (atom < count) ? ev4[c] : 0.f;
        }
        *(f32x4*)(out + (size_t)b * 384 + t * 4) = o4;
    }
    float lp = 0.f;
    if (t < NATOM && t < count) {
        const int j = t;
        const float* ev = evala + ((size_t)b * NATOM + j) * 3;
        float e0v = ev[0], e1v = ev[1], e2v = ev[2];
        float scale = scale_ptr[0];
        float ax = amBs[j * 3 + 0], ay = amBs[j * 3 + 1], az = amBs[j * 3 + 2];
        float nrm = sqrtf(fmaf(ax, ax, fmaf(ay, ay, az * az)) + 1e-16f) + 1e-8f;
        float qe = __expf(-2.f * nrm);
        float th = (1.f - qe) / (1.f + qe);
        float sc = th / nrm * scale;
        float mux = ax * sc, muy = ay * sc, muz = az * sc;
        float ls = fminf(fmaxf(lsBs[j], -20.f), 2.f);
        float sig = __expf(ls) * scale;
        float sinv = 1.f / sig;
        float lsg = __logf(sig);
        float zx = (e0v - mux) * sinv;
        float zy = (e1v - muy) * sinv;
        float zz = (e2v - muz) * sinv;
        lp = -0.5f * (zx * zx + zy * zy + zz * zz) - 3.f * lsg
             - 3.f * 0.91893853320467274f;
    }
    #pragma unroll
    for (int off = 32; off > 0; off >>= 1) lp += __shfl_down(lp, off);
    if (t == 0)  redBs[0] = lp;
    if (t == 64) redBs[1] = lp;
    __syncthreads();                 // B5
    if (t == 0) out[(size_t)NBATCH * NATOM * 3 + b] = redBs[0] + redBs[1];
}

extern "C" void kernel_launch(void* const* d_in, const int* in_sizes, int n_in,
                              void* d_out, int out_size, void* d_ws, size_t ws_size,
                              hipStream_t stream) {
    const float* kx    = (const float*)d_in[0];
    const float* pos   = (const float*)d_in[1];
    const float* mask  = (const float*)d_in[2];
    const float* scale = (const float*)d_in[3];
    const float* ev    = (const float*)d_in[4];
    const float* Wx    = (const float*)d_in[5];
    const float* bx    = (const float*)d_in[6];
    const float* Wk    = (const float*)d_in[7];
    const float* bk    = (const float*)d_in[8];
    float* out = (float*)d_out;
    unsigned short* ws = (unsigned short*)d_ws;

    // W hi/lo split (128KB in d_ws), recomputed each launch (deterministic)
    hipLaunchKernelGGL(wsplit_kernel, dim3(128), dim3(256), 0, stream, Wx, Wk, ws);

    const size_t shbytes = 65536;   // 2 planes x 32KB dynamic LDS -> 2 blocks/CU
    (void)hipFuncSetAttribute((const void*)gen_actions_kernel,
                              hipFuncAttributeMaxDynamicSharedMemorySize,
                              (int)shbytes);
    hipLaunchKernelGGL(gen_actions_kernel, dim3(NBATCH), dim3(THREADS), shbytes, stream,
                       kx, pos, mask, scale, ev, bx, bk, ws, out);
}